// Round 5
// baseline (100.423 us; speedup 1.0000x reference)
//
#include <hip/hip_runtime.h>

// RainKAN fused forward via MFMA f16, register-built A-fragments, M=64/block.
//   X[B, K=2016] x W[K,64] -> h[B,64] -> exact fp32 KAN layer 2 -> out[B]
// K-order: steps 0..62 (32 k each). Steps 0..6: silu slots, k = st*32+kg*8+j -> input i=k.
// Steps 7..62: spline slots, input i = (st-7)*4 + kg, basis g = j.
// A-frag (16x16x32 f16): lane(m=lane&15, kg=lane>>4) holds k=kg*8+j -> for a spline step
// that's all 8 bases of ONE x -> built in registers from one LDS x read. No feature LDS.
// Wave (mh, kh): m-half mh (32 samples = 2 m-tiles), K-parity kh. B-frags double-buffered
// in registers so L2 loads for step t+2 are in flight during step t's VALU/MFMA.
// W prepped into d_ws fp16 B-frag order: element(st,nt,lane,j) = W[st*32+(lane>>4)*8+j][nt*16+(lane&15)].

typedef _Float16 half8 __attribute__((ext_vector_type(8)));
typedef float floatx4 __attribute__((ext_vector_type(4)));

#define XR 233   // x-row stride in floats (233%32=9 -> <=2-way LDS conflicts)

__device__ __forceinline__ float silu_f(float x) {
    return x / (1.0f + __expf(-x));
}

__device__ __forceinline__ void bspline8_dense(float x, float f[8]) {
    float u  = (x + 2.2f) * 2.5f;
    float fj = floorf(u);
    float t  = u - fj;
    int   j  = (int)fj;
    bool valid = (u >= 0.0f) && (u < 11.0f);
    float t2 = t * t, t3 = t2 * t, omt = 1.0f - t;
    float b0 = omt * omt * omt * (1.0f / 6.0f);
    float b1 = (3.0f * t3 - 6.0f * t2 + 4.0f) * (1.0f / 6.0f);
    float b2 = (-3.0f * t3 + 3.0f * t2 + 3.0f * t + 1.0f) * (1.0f / 6.0f);
    float b3 = t3 * (1.0f / 6.0f);
    if (!valid) { b0 = b1 = b2 = b3 = 0.0f; }
    int base = j - 3;
#pragma unroll
    for (int g = 0; g < 8; ++g) {
        int m = g - base;
        float v = (m == 0) ? b0 : 0.0f;
        v = (m == 1) ? b1 : v;
        v = (m == 2) ? b2 : v;
        v = (m == 3) ? b3 : v;
        f[g] = v;
    }
}

// f16 A-fragment: 4 bases placed at slots (j-3)..j via 128-bit shift
__device__ __forceinline__ half8 bspline_frag(float x) {
    float u  = (x + 2.2f) * 2.5f;
    float fj = floorf(u);
    float t  = u - fj;
    int   j  = (int)fj;
    bool valid = (u >= 0.0f) && (u < 11.0f);
    float t2 = t * t, t3 = t2 * t, omt = 1.0f - t;
    float b0 = omt * omt * omt * (1.0f / 6.0f);
    float b1 = (3.0f * t3 - 6.0f * t2 + 4.0f) * (1.0f / 6.0f);
    float b2 = (-3.0f * t3 + 3.0f * t2 + 3.0f * t + 1.0f) * (1.0f / 6.0f);
    float b3 = t3 * (1.0f / 6.0f);
    union { _Float16 h[4]; unsigned long long q; } p;
    p.h[0] = (_Float16)b0; p.h[1] = (_Float16)b1;
    p.h[2] = (_Float16)b2; p.h[3] = (_Float16)b3;
    unsigned long long lo = valid ? p.q : 0ull;
    int jc = valid ? j : 3;
    int sh = (jc - 3) * 16;              // bits, in [-48, 112]
    unsigned long long rlo, rhi;
    if (sh >= 0) {
        rlo = (sh < 64) ? (lo << sh) : 0ull;
        rhi = (sh == 0) ? 0ull
            : (sh < 64) ? (lo >> (64 - sh))
                        : (lo << (sh - 64));
    } else {
        rlo = lo >> (-sh);
        rhi = 0ull;
    }
    union { unsigned long long q[2]; half8 v; } r;
    r.q[0] = rlo; r.q[1] = rhi;
    return r.v;
}

// ---- prep: wb1[219,64] + cf1[219,64,8] -> fp16 B-frag wcat[129024] (258 KB) ----
__global__ __launch_bounds__(256) void build_w(
    const float* __restrict__ wb1, const float* __restrict__ cf1,
    _Float16* __restrict__ wcat)
{
    int flat = blockIdx.x * 256 + threadIdx.x;   // < 63*4*64 = 16128
    int lane = flat & 63;
    int nt   = (flat >> 6) & 3;
    int st   = flat >> 8;                        // 0..62
    int kg   = lane >> 4;
    int n    = nt * 16 + (lane & 15);
    _Float16 v[8];
    if (st < 7) {
#pragma unroll
        for (int j = 0; j < 8; ++j) {
            int i = st * 32 + kg * 8 + j;
            v[j] = (_Float16)((i < 219) ? wb1[i * 64 + n] : 0.0f);
        }
    } else {
        int i = (st - 7) * 4 + kg;
#pragma unroll
        for (int j = 0; j < 8; ++j)
            v[j] = (_Float16)((i < 219) ? cf1[(i * 64 + n) * 8 + j] : 0.0f);
    }
    *(half8*)(wcat + (size_t)flat * 8) = *(half8*)v;
}

// ---- fused GEMM + layer 2: 256 blocks x 256 threads, 64 samples/block ----
__global__ __launch_bounds__(256) void kan_mfma(
    const float* __restrict__ hist,    // [B,192]
    const float* __restrict__ statf,   // [B,3]
    const float* __restrict__ timef,   // [B,8]
    const int*   __restrict__ st_idx,  // [B]
    const float* __restrict__ emb,     // [120,16]
    const _Float16* __restrict__ wcat, // [129024]
    const float* __restrict__ wb2,     // [64]
    const float* __restrict__ cf2,     // [64,8]
    float* __restrict__ out)           // [B]
{
    __shared__ union {
        float xb[64 * XR];                                      // 59648 B
        struct { float h[2][64 * 65]; float part[4 * 64]; } ep; // 34304 B
    } sm;

    const int tid  = threadIdx.x;
    const int lane = tid & 63;
    const int w    = __builtin_amdgcn_readfirstlane(tid >> 6);
    const int mh   = w & 1;            // m-half: samples mh*32 .. +32
    const int kh   = w >> 1;           // K-step parity
    const int bx   = blockIdx.x;
    const int row  = lane & 15;
    const int kg   = lane >> 4;

    // ---- stage raw x[64][224] into LDS ----
    {
        const int s = tid >> 2, q4 = tid & 3;
        const int b = bx * 64 + s;
        const float4* h4 = (const float4*)hist;   // 48 float4 per row
#pragma unroll
        for (int f = 0; f < 12; ++f) {
            int i4 = q4 + 4 * f;                  // 0..47
            float4 v = h4[b * 48 + i4];
            sm.xb[s * XR + i4 * 4 + 0] = v.x;
            sm.xb[s * XR + i4 * 4 + 1] = v.y;
            sm.xb[s * XR + i4 * 4 + 2] = v.z;
            sm.xb[s * XR + i4 * 4 + 3] = v.w;
        }
    }
#pragma unroll
    for (int f = 0; f < 8; ++f) {
        int flat = f * 256 + tid;                 // < 2048
        int s  = flat >> 5;
        int ii = 192 + (flat & 31);               // 192..223
        int b  = bx * 64 + s;
        float v;
        if (ii < 195)      v = statf[b * 3 + (ii - 192)];
        else if (ii < 203) v = timef[b * 8 + (ii - 195)];
        else if (ii < 219) v = emb[st_idx[b] * 16 + (ii - 203)];
        else               v = 0.0f;
        sm.xb[s * XR + ii] = v;
    }
    __syncthreads();

    const float* xrow0 = &sm.xb[(mh * 32 + row) * XR];        // m-tile 0 of this half
    const float* xrow1 = xrow0 + 16 * XR;                     // m-tile 1

    floatx4 acc[2][4];
#pragma unroll
    for (int m = 0; m < 2; ++m)
#pragma unroll
        for (int nt = 0; nt < 4; ++nt) acc[m][nt] = (floatx4){0.f, 0.f, 0.f, 0.f};

    // ---- silu steps (st = kh, kh+2, ... < 7) ----
    for (int st = kh; st < 7; st += 2) {
        const _Float16* wp = wcat + (size_t)(st * 4) * 512 + lane * 8;
        half8 bf0 = *(const half8*)(wp);
        half8 bf1 = *(const half8*)(wp + 512);
        half8 bf2 = *(const half8*)(wp + 1024);
        half8 bf3 = *(const half8*)(wp + 1536);
        const int i0 = st * 32 + kg * 8;
        half8 a0, a1;
#pragma unroll
        for (int jj = 0; jj < 8; ++jj) {
            a0[jj] = (_Float16)silu_f(xrow0[i0 + jj]);
            a1[jj] = (_Float16)silu_f(xrow1[i0 + jj]);
        }
        acc[0][0] = __builtin_amdgcn_mfma_f32_16x16x32_f16(a0, bf0, acc[0][0], 0, 0, 0);
        acc[0][1] = __builtin_amdgcn_mfma_f32_16x16x32_f16(a0, bf1, acc[0][1], 0, 0, 0);
        acc[0][2] = __builtin_amdgcn_mfma_f32_16x16x32_f16(a0, bf2, acc[0][2], 0, 0, 0);
        acc[0][3] = __builtin_amdgcn_mfma_f32_16x16x32_f16(a0, bf3, acc[0][3], 0, 0, 0);
        acc[1][0] = __builtin_amdgcn_mfma_f32_16x16x32_f16(a1, bf0, acc[1][0], 0, 0, 0);
        acc[1][1] = __builtin_amdgcn_mfma_f32_16x16x32_f16(a1, bf1, acc[1][1], 0, 0, 0);
        acc[1][2] = __builtin_amdgcn_mfma_f32_16x16x32_f16(a1, bf2, acc[1][2], 0, 0, 0);
        acc[1][3] = __builtin_amdgcn_mfma_f32_16x16x32_f16(a1, bf3, acc[1][3], 0, 0, 0);
    }

    // ---- spline steps (st >= 7, parity kh), B-frags double-buffered in regs ----
    {
        int st = (kh == 1) ? 7 : 8;
        const _Float16* wp = wcat + (size_t)(st * 4) * 512 + lane * 8;
        half8 bf0 = *(const half8*)(wp);
        half8 bf1 = *(const half8*)(wp + 512);
        half8 bf2 = *(const half8*)(wp + 1024);
        half8 bf3 = *(const half8*)(wp + 1536);
        for (; st < 63; st += 2) {
            const int stn = (st + 2 < 63) ? st + 2 : st;     // clamped redundant tail load
            const _Float16* wn = wcat + (size_t)(stn * 4) * 512 + lane * 8;
            half8 n0 = *(const half8*)(wn);
            half8 n1 = *(const half8*)(wn + 512);
            half8 n2 = *(const half8*)(wn + 1024);
            half8 n3 = *(const half8*)(wn + 1536);
            const int xo = (st - 7) * 4 + kg;
            float x0 = xrow0[xo];
            float x1 = xrow1[xo];
            half8 a0 = bspline_frag(x0);
            half8 a1 = bspline_frag(x1);
            acc[0][0] = __builtin_amdgcn_mfma_f32_16x16x32_f16(a0, bf0, acc[0][0], 0, 0, 0);
            acc[0][1] = __builtin_amdgcn_mfma_f32_16x16x32_f16(a0, bf1, acc[0][1], 0, 0, 0);
            acc[0][2] = __builtin_amdgcn_mfma_f32_16x16x32_f16(a0, bf2, acc[0][2], 0, 0, 0);
            acc[0][3] = __builtin_amdgcn_mfma_f32_16x16x32_f16(a0, bf3, acc[0][3], 0, 0, 0);
            acc[1][0] = __builtin_amdgcn_mfma_f32_16x16x32_f16(a1, bf0, acc[1][0], 0, 0, 0);
            acc[1][1] = __builtin_amdgcn_mfma_f32_16x16x32_f16(a1, bf1, acc[1][1], 0, 0, 0);
            acc[1][2] = __builtin_amdgcn_mfma_f32_16x16x32_f16(a1, bf2, acc[1][2], 0, 0, 0);
            acc[1][3] = __builtin_amdgcn_mfma_f32_16x16x32_f16(a1, bf3, acc[1][3], 0, 0, 0);
            bf0 = n0; bf1 = n1; bf2 = n2; bf3 = n3;
        }
    }

    // ---- epilogue: h partials to LDS (C/D: col=lane&15, row=(lane>>4)*4+reg) ----
    __syncthreads();   // all waves done reading xb before overwrite
#pragma unroll
    for (int m = 0; m < 2; ++m) {
#pragma unroll
        for (int nt = 0; nt < 4; ++nt) {
#pragma unroll
            for (int r = 0; r < 4; ++r) {
                const int rr = mh * 32 + m * 16 + kg * 4 + r;
                const int cc = nt * 16 + row;
                sm.ep.h[kh][rr * 65 + cc] = acc[m][nt][r];
            }
        }
    }
    __syncthreads();

    // ---- exact fp32 layer 2: thread (s = tid&63, og = tid>>6) -> outputs og*16..+16 ----
    {
        const int s  = tid & 63;
        const int og = tid >> 6;
        float psum = 0.0f;
#pragma unroll
        for (int oo = 0; oo < 16; ++oo) {
            const int o = og * 16 + oo;
            float h = sm.ep.h[0][s * 65 + o] + sm.ep.h[1][s * 65 + o];
            psum = fmaf(silu_f(h), wb2[o], psum);
            float f2[8];
            bspline8_dense(h, f2);
#pragma unroll
            for (int g = 0; g < 8; ++g)
                psum = fmaf(f2[g], cf2[o * 8 + g], psum);
        }
        sm.ep.part[og * 64 + s] = psum;
    }
    __syncthreads();
    if (tid < 64)
        out[bx * 64 + tid] = sm.ep.part[tid] + sm.ep.part[64 + tid] +
                             sm.ep.part[128 + tid] + sm.ep.part[192 + tid];
}

extern "C" void kernel_launch(void* const* d_in, const int* in_sizes, int n_in,
                              void* d_out, int out_size, void* d_ws, size_t ws_size,
                              hipStream_t stream) {
    const float* hist  = (const float*)d_in[0];
    const float* statf = (const float*)d_in[1];
    const float* timef = (const float*)d_in[2];
    const int*   stidx = (const int*)  d_in[3];
    const float* emb   = (const float*)d_in[4];
    const float* wb1   = (const float*)d_in[5];
    const float* cf1   = (const float*)d_in[6];
    const float* wb2   = (const float*)d_in[7];
    const float* cf2   = (const float*)d_in[8];
    float* out = (float*)d_out;

    _Float16* wcat = (_Float16*)d_ws;   // 129024 fp16 = 258 KB

    build_w<<<63, 256, 0, stream>>>(wb1, cf1, wcat);
    kan_mfma<<<256, 256, 0, stream>>>(hist, statf, timef, stidx, emb,
                                      wcat, wb2, cf2, out);
}

// Round 6
// 93.050 us; speedup vs baseline: 1.0792x; 1.0792x over previous
//
#include <hip/hip_runtime.h>

// RainKAN fused forward via MFMA f16, register-built A-fragments.
//   X[B, K=2048pad] x W[K,64] -> h[B,64] -> exact fp32 KAN layer 2 -> out[B]
// K-steps 0..63 (32 k each; step 63 = zero pad). Steps 0..6: silu slots,
// k = st*32+kg*8+j -> input i=k. Steps 7..63: spline slots, input i=(st-7)*4+kg, basis j.
// A-frag (16x16x32 f16): lane(m=lane&15, kg=lane>>4) holds k=kg*8+j -> spline step needs
// all 8 bases of ONE x -> built in registers from one LDS x read. No feature LDS.
// Block: M=16 samples, 4 waves = 4 K-quarters (wave q: st ≡ q mod 4, 16 steps each).
// 1024 blocks -> 4 blocks/CU, 4 waves/SIMD: TLP hides L2 B-frag latency.
// W prepped into d_ws fp16 B-frag order: elem(st,nt,lane,j)=W[st*32+(lane>>4)*8+j][nt*16+(lane&15)].

typedef _Float16 half8 __attribute__((ext_vector_type(8)));
typedef float floatx4 __attribute__((ext_vector_type(4)));

#define XR 233   // x-row stride in floats (233%32=9 -> <=2-way LDS read conflicts)

__device__ __forceinline__ float silu_f(float x) {
    return x / (1.0f + __expf(-x));
}

__device__ __forceinline__ void bspline8_dense(float x, float f[8]) {
    float u  = (x + 2.2f) * 2.5f;
    float fj = floorf(u);
    float t  = u - fj;
    int   j  = (int)fj;
    bool valid = (u >= 0.0f) && (u < 11.0f);
    float t2 = t * t, t3 = t2 * t, omt = 1.0f - t;
    float b0 = omt * omt * omt * (1.0f / 6.0f);
    float b1 = (3.0f * t3 - 6.0f * t2 + 4.0f) * (1.0f / 6.0f);
    float b2 = (-3.0f * t3 + 3.0f * t2 + 3.0f * t + 1.0f) * (1.0f / 6.0f);
    float b3 = t3 * (1.0f / 6.0f);
    if (!valid) { b0 = b1 = b2 = b3 = 0.0f; }
    int base = j - 3;
#pragma unroll
    for (int g = 0; g < 8; ++g) {
        int m = g - base;
        float v = (m == 0) ? b0 : 0.0f;
        v = (m == 1) ? b1 : v;
        v = (m == 2) ? b2 : v;
        v = (m == 3) ? b3 : v;
        f[g] = v;
    }
}

// f16 A-fragment: 4 bases placed at slots (j-3)..j via 128-bit shift
__device__ __forceinline__ half8 bspline_frag(float x) {
    float u  = (x + 2.2f) * 2.5f;
    float fj = floorf(u);
    float t  = u - fj;
    int   j  = (int)fj;
    bool valid = (u >= 0.0f) && (u < 11.0f);
    float t2 = t * t, t3 = t2 * t, omt = 1.0f - t;
    float b0 = omt * omt * omt * (1.0f / 6.0f);
    float b1 = (3.0f * t3 - 6.0f * t2 + 4.0f) * (1.0f / 6.0f);
    float b2 = (-3.0f * t3 + 3.0f * t2 + 3.0f * t + 1.0f) * (1.0f / 6.0f);
    float b3 = t3 * (1.0f / 6.0f);
    union { _Float16 h[4]; unsigned long long q; } p;
    p.h[0] = (_Float16)b0; p.h[1] = (_Float16)b1;
    p.h[2] = (_Float16)b2; p.h[3] = (_Float16)b3;
    unsigned long long lo = valid ? p.q : 0ull;
    int jc = valid ? j : 3;
    int sh = (jc - 3) * 16;              // bits, in [-48, 112]
    unsigned long long rlo, rhi;
    if (sh >= 0) {
        rlo = (sh < 64) ? (lo << sh) : 0ull;
        rhi = (sh == 0) ? 0ull
            : (sh < 64) ? (lo >> (64 - sh))
                        : (lo << (sh - 64));
    } else {
        rlo = lo >> (-sh);
        rhi = 0ull;
    }
    union { unsigned long long q[2]; half8 v; } r;
    r.q[0] = rlo; r.q[1] = rhi;
    return r.v;
}

// ---- prep: wb1[219,64] + cf1[219,64,8] -> fp16 B-frag wcat[131072] (256 KB) ----
__global__ __launch_bounds__(256) void build_w(
    const float* __restrict__ wb1, const float* __restrict__ cf1,
    _Float16* __restrict__ wcat)
{
    int flat = blockIdx.x * 256 + threadIdx.x;   // < 64*4*64 = 16384
    int lane = flat & 63;
    int nt   = (flat >> 6) & 3;
    int st   = flat >> 8;                        // 0..63
    int kg   = lane >> 4;
    int n    = nt * 16 + (lane & 15);
    _Float16 v[8];
    if (st < 7) {
#pragma unroll
        for (int j = 0; j < 8; ++j) {
            int i = st * 32 + kg * 8 + j;
            v[j] = (_Float16)((i < 219) ? wb1[i * 64 + n] : 0.0f);
        }
    } else {
        int i = (st - 7) * 4 + kg;
#pragma unroll
        for (int j = 0; j < 8; ++j)
            v[j] = (_Float16)((i < 219) ? cf1[(i * 64 + n) * 8 + j] : 0.0f);
    }
    *(half8*)(wcat + (size_t)flat * 8) = *(half8*)v;
}

// ---- fused GEMM + layer 2: 1024 blocks x 256 threads, 16 samples/block ----
__global__ __launch_bounds__(256, 4) void kan_mfma(
    const float* __restrict__ hist,    // [B,192]
    const float* __restrict__ statf,   // [B,3]
    const float* __restrict__ timef,   // [B,8]
    const int*   __restrict__ st_idx,  // [B]
    const float* __restrict__ emb,     // [120,16]
    const _Float16* __restrict__ wcat, // [131072]
    const float* __restrict__ wb2,     // [64]
    const float* __restrict__ cf2,     // [64,8]
    float* __restrict__ out)           // [B]
{
    __shared__ union {
        float xb[16 * XR];                                      // 14912 B
        struct { float h[4][16 * 65]; float part[16 * 16]; } ep; // 17664 B
    } sm;

    const int tid  = threadIdx.x;
    const int lane = tid & 63;
    const int q    = __builtin_amdgcn_readfirstlane(tid >> 6);  // K-quarter
    const int bx   = blockIdx.x;
    const int row  = lane & 15;
    const int kg   = lane >> 4;

    // ---- stage raw x[16][233] into LDS (slots 219..232 zeroed) ----
    {
        const int s = tid >> 4, c = tid & 15;
        const int b = bx * 16 + s;
        const float4* h4 = (const float4*)hist;   // 48 float4 per row
#pragma unroll
        for (int f = 0; f < 3; ++f) {
            int i4 = c + 16 * f;                  // 0..47
            float4 v = h4[b * 48 + i4];
            sm.xb[s * XR + i4 * 4 + 0] = v.x;
            sm.xb[s * XR + i4 * 4 + 1] = v.y;
            sm.xb[s * XR + i4 * 4 + 2] = v.z;
            sm.xb[s * XR + i4 * 4 + 3] = v.w;
        }
    }
#pragma unroll
    for (int f = 0; f < 3; ++f) {
        int flat = f * 256 + tid;                 // < 768 = 16*48
        int s  = flat / 48;
        int ii = 192 + (flat % 48);               // 192..239
        int b  = bx * 16 + s;
        float v;
        if (ii < 195)      v = statf[b * 3 + (ii - 192)];
        else if (ii < 203) v = timef[b * 8 + (ii - 195)];
        else if (ii < 219) v = emb[st_idx[b] * 16 + (ii - 203)];
        else               v = 0.0f;
        if (ii < 233) sm.xb[s * XR + ii] = v;
    }
    __syncthreads();

    const float* xrow = &sm.xb[row * XR];

    floatx4 acc[4];
#pragma unroll
    for (int nt = 0; nt < 4; ++nt) acc[nt] = (floatx4){0.f, 0.f, 0.f, 0.f};

    // ---- silu steps: st = q, q+4, ... < 7 ----
    for (int st = q; st < 7; st += 4) {
        const _Float16* wp = wcat + (size_t)(st * 4) * 512 + lane * 8;
        half8 bf0 = *(const half8*)(wp);
        half8 bf1 = *(const half8*)(wp + 512);
        half8 bf2 = *(const half8*)(wp + 1024);
        half8 bf3 = *(const half8*)(wp + 1536);
        const int i0 = st * 32 + kg * 8;
        half8 af;
#pragma unroll
        for (int jj = 0; jj < 8; ++jj)
            af[jj] = (_Float16)silu_f(xrow[i0 + jj]);
        acc[0] = __builtin_amdgcn_mfma_f32_16x16x32_f16(af, bf0, acc[0], 0, 0, 0);
        acc[1] = __builtin_amdgcn_mfma_f32_16x16x32_f16(af, bf1, acc[1], 0, 0, 0);
        acc[2] = __builtin_amdgcn_mfma_f32_16x16x32_f16(af, bf2, acc[2], 0, 0, 0);
        acc[3] = __builtin_amdgcn_mfma_f32_16x16x32_f16(af, bf3, acc[3], 0, 0, 0);
    }

    // ---- spline steps: st >= 7, st ≡ q (mod 4), through padded step 63 ----
    {
        int st = 7 + ((q - 3) & 3);               // first st>=7 with st%4==q
#pragma unroll 2
        for (; st < 64; st += 4) {
            const _Float16* wp = wcat + (size_t)(st * 4) * 512 + lane * 8;
            half8 bf0 = *(const half8*)(wp);
            half8 bf1 = *(const half8*)(wp + 512);
            half8 bf2 = *(const half8*)(wp + 1024);
            half8 bf3 = *(const half8*)(wp + 1536);
            float x = xrow[(st - 7) * 4 + kg];
            half8 af = bspline_frag(x);
            acc[0] = __builtin_amdgcn_mfma_f32_16x16x32_f16(af, bf0, acc[0], 0, 0, 0);
            acc[1] = __builtin_amdgcn_mfma_f32_16x16x32_f16(af, bf1, acc[1], 0, 0, 0);
            acc[2] = __builtin_amdgcn_mfma_f32_16x16x32_f16(af, bf2, acc[2], 0, 0, 0);
            acc[3] = __builtin_amdgcn_mfma_f32_16x16x32_f16(af, bf3, acc[3], 0, 0, 0);
        }
    }

    // ---- epilogue: per-quarter h partials (C/D: col=lane&15, row=(lane>>4)*4+reg) ----
    __syncthreads();   // xb reads done before overwrite
#pragma unroll
    for (int nt = 0; nt < 4; ++nt) {
#pragma unroll
        for (int r = 0; r < 4; ++r) {
            const int rr = kg * 4 + r;            // 0..15
            const int cc = nt * 16 + row;         // 0..63
            sm.ep.h[q][rr * 65 + cc] = acc[nt][r];
        }
    }
    __syncthreads();

    // ---- exact fp32 layer 2: thread (s = tid&15, og = tid>>4) -> outputs og*4..+4 ----
    {
        const int s  = tid & 15;
        const int og = tid >> 4;                  // 0..15
        float psum = 0.0f;
#pragma unroll
        for (int oo = 0; oo < 4; ++oo) {
            const int o = og * 4 + oo;
            float h = sm.ep.h[0][s * 65 + o] + sm.ep.h[1][s * 65 + o]
                    + sm.ep.h[2][s * 65 + o] + sm.ep.h[3][s * 65 + o];
            psum = fmaf(silu_f(h), wb2[o], psum);
            float f2[8];
            bspline8_dense(h, f2);
#pragma unroll
            for (int g = 0; g < 8; ++g)
                psum = fmaf(f2[g], cf2[o * 8 + g], psum);
        }
        sm.ep.part[og * 16 + s] = psum;
    }
    __syncthreads();
    if (tid < 16) {
        float r = 0.0f;
#pragma unroll
        for (int og = 0; og < 16; ++og) r += sm.ep.part[og * 16 + tid];
        out[bx * 16 + tid] = r;
    }
}

extern "C" void kernel_launch(void* const* d_in, const int* in_sizes, int n_in,
                              void* d_out, int out_size, void* d_ws, size_t ws_size,
                              hipStream_t stream) {
    const float* hist  = (const float*)d_in[0];
    const float* statf = (const float*)d_in[1];
    const float* timef = (const float*)d_in[2];
    const int*   stidx = (const int*)  d_in[3];
    const float* emb   = (const float*)d_in[4];
    const float* wb1   = (const float*)d_in[5];
    const float* cf1   = (const float*)d_in[6];
    const float* wb2   = (const float*)d_in[7];
    const float* cf2   = (const float*)d_in[8];
    float* out = (float*)d_out;

    _Float16* wcat = (_Float16*)d_ws;   // 131072 fp16 = 256 KB

    build_w<<<64, 256, 0, stream>>>(wb1, cf1, wcat);
    kan_mfma<<<1024, 256, 0, stream>>>(hist, statf, timef, stidx, emb,
                                       wcat, wb2, cf2, out);
}